// Round 16
// baseline (143.442 us; speedup 1.0000x reference)
//
#include <hip/hip_runtime.h>
#include <hip/hip_fp16.h>

#define IN_DIM  16
#define HID_DIM 64
#define OUT_DIM 32

#define CAP   8192  // per-bucket capacity in gpart (mean 4096, +64 sigma)
#define EPB   3328  // edges per partA block = 256 threads x 13 regs
#define CONVB 64    // extra partA blocks that convert x -> fp16

// ---------------------------------------------------------------------------
// Edge dtype: reference says int64, harness doc says int32. Detect inline:
// nonneg int64 < 2^31 has every odd 32-bit word == 0.
// ---------------------------------------------------------------------------
__device__ __forceinline__ int detect_is64(const void* edges) {
    const int* w = (const int*)edges;
    int is64 = 1;
    #pragma unroll
    for (int i = 0; i < 16; ++i) is64 &= (w[2 * i + 1] == 0);
    return is64;
}

__device__ __forceinline__ long long edge_at(const void* edges, int is64, long long i) {
    if (is64) return ((const long long*)edges)[i];
    return (long long)((const int*)edges)[i];
}

// ---------------------------------------------------------------------------
// partA: coarse partition by dst>>8 into per-bucket private regions of gpart.
// Blocks >= nblkA convert x -> fp16 (ride-along). Entry: src|((dst&255)<<16).
// Flush: parallel atomic reserve (1 thread/bucket, all in flight), then
// wave-cooperative coalesced stores per bucket run.
// ---------------------------------------------------------------------------
__global__ __launch_bounds__(256) void k_partA(const void* edges, int* gcur,
                                               unsigned int* gpart, int nbuk, long long E,
                                               const float* __restrict__ x,
                                               __half* __restrict__ xh,
                                               long long xElems, int nblkA) {
    if (blockIdx.x >= nblkA) {
        // x -> fp16 conversion, grid-stride, coalesced
        const float4* x4 = (const float4*)x;
        uint2* outp = (uint2*)xh;
        long long n4 = xElems >> 2;
        for (long long i = (long long)(blockIdx.x - nblkA) * 256 + threadIdx.x;
             i < n4; i += (long long)CONVB * 256) {
            float4 v = x4[i];
            __half2 a = __floats2half2_rn(v.x, v.y);
            __half2 b = __floats2half2_rn(v.z, v.w);
            outp[i] = make_uint2(*(unsigned int*)&a, *(unsigned int*)&b);
        }
        return;
    }

    __shared__ unsigned int staged[EPB];     // 13 KB
    __shared__ int hcnt[256], hoff[256], hcur[256], hbase[256];
    __shared__ int s64s;
    int t = threadIdx.x;
    if (t == 0) s64s = detect_is64(edges);
    hcnt[t] = 0;
    __syncthreads();
    int is64 = s64s;

    long long e0 = (long long)blockIdx.x * EPB;
    unsigned int rs[13], rd[13];
    int nval = 0;
    #pragma unroll
    for (int k = 0; k < 13; ++k) {
        long long e = e0 + t + k * 256;
        if (e < E) {
            rs[k] = (unsigned int)edge_at(edges, is64, e);
            rd[k] = (unsigned int)edge_at(edges, is64, E + e);
            atomicAdd(&hcnt[rd[k] >> 8], 1);
            nval = k + 1;
        }
    }
    __syncthreads();

    // inclusive scan of hcnt -> exclusive offsets (hcnt preserved)
    int v = hcnt[t];
    hoff[t] = v;
    __syncthreads();
    for (int d = 1; d < 256; d <<= 1) {
        int u = (t >= d) ? hoff[t - d] : 0;
        __syncthreads();
        hoff[t] += u;
        __syncthreads();
    }
    int excl = hoff[t] - v;
    hoff[t] = excl;
    hcur[t] = excl;
    __syncthreads();

    #pragma unroll
    for (int k = 0; k < 13; ++k) {
        if (k < nval) {
            int p = atomicAdd(&hcur[rd[k] >> 8], 1);
            staged[p] = rs[k] | ((rd[k] & 255u) << 16);
        }
    }
    // reserve global space: all bucket atomics issued in parallel
    if (t < nbuk) {
        int c = hcnt[t];
        hbase[t] = (c > 0) ? atomicAdd(&gcur[t], c) : 0;
    }
    __syncthreads();

    // wave-cooperative coalesced flush
    int wid = t >> 6, lane = t & 63;
    for (int b = wid; b < nbuk; b += 4) {
        int c = hcnt[b], o = hoff[b], base = hbase[b];
        for (int oo = lane; oo < c; oo += 64) {
            int idx = base + oo;
            if (idx < CAP) gpart[(size_t)b * CAP + idx] = staged[o + oo];
        }
    }
}

// ---------------------------------------------------------------------------
// partB: one block per bucket. Contiguous coalesced read of the bucket's CAP
// region; fine-sort by dst&255; writes dinv/offs and u16 src csr.
// Requires nbuk <= 256 and N <= 65536.
// ---------------------------------------------------------------------------
__global__ __launch_bounds__(256) void k_partB(const int* __restrict__ gcur,
                                               const unsigned int* __restrict__ gpart,
                                               unsigned short* __restrict__ csr,
                                               int* __restrict__ offs,
                                               float* __restrict__ dinv,
                                               int nbuk, int N) {
    __shared__ unsigned int ebuf[CAP];       // 32 KB
    __shared__ int bscan[256];
    __shared__ int hcnt[256], hoff[256], hcur[256];
    int t = threadIdx.x;
    int b = blockIdx.x;

    // redundant scan of bucket counts -> this bucket's global base
    int bc = (t < nbuk) ? min(gcur[t], CAP) : 0;
    bscan[t] = bc;
    hcnt[t] = 0;
    __syncthreads();
    for (int d = 1; d < 256; d <<= 1) {
        int u = (t >= d) ? bscan[t - d] : 0;
        __syncthreads();
        bscan[t] += u;
        __syncthreads();
    }
    int base = (b == 0) ? 0 : bscan[b - 1];
    int cnt  = bscan[b] - base;

    for (int i = t; i < cnt; i += 256) ebuf[i] = gpart[(size_t)b * CAP + i];
    __syncthreads();
    for (int i = t; i < cnt; i += 256) atomicAdd(&hcnt[(ebuf[i] >> 16) & 255u], 1);
    __syncthreads();

    int v = hcnt[t];
    hoff[t] = v;
    __syncthreads();
    for (int d = 1; d < 256; d <<= 1) {
        int u = (t >= d) ? hoff[t - d] : 0;
        __syncthreads();
        hoff[t] += u;
        __syncthreads();
    }
    int excl = hoff[t] - v;
    hcur[t] = excl;
    __syncthreads();

    int node = b * 256 + t;
    if (node < N) {
        offs[node] = base + excl;
        dinv[node] = rsqrtf((float)v + 1.0f);
    }
    if (b == nbuk - 1 && t == 0) offs[N] = bscan[nbuk - 1];

    // scatter u16 src into this bucket's private csr window
    for (int i = t; i < cnt; i += 256) {
        unsigned int e = ebuf[i];
        int dl = (e >> 16) & 255;
        int p = atomicAdd(&hcur[dl], 1);
        csr[base + p] = (unsigned short)(e & 0xffffu);
    }
}

// ---------------------------------------------------------------------------
// Layer-1 gather (fp16 x): 4 nodes per wave; each node owns 16 lanes =
// 2 comps (uint4 = 8 fp16 ch of the 32 B row) x 8 edge-ways.
// aggX[i][:] = di*(di*x_i + sum_s dinv_s*x_s)   (fp32 out)
// ---------------------------------------------------------------------------
__global__ __launch_bounds__(256) void k_agg1(
    const __half* __restrict__ xh, const float* __restrict__ dinv,
    const int* __restrict__ offs, const unsigned short* __restrict__ csr,
    float* __restrict__ aggX, int N)
{
    int gtid = blockIdx.x * 256 + threadIdx.x;
    int lane = gtid & 63;
    int g = lane >> 4, sub = lane & 15;
    int comp = sub >> 3;     // 0..1 : which 8-channel (16 B) half of the row
    int way  = sub & 7;      // 0..7 edge ways
    int node = (gtid >> 6) * 4 + g;
    if (node >= N) return;
    const uint4* x2 = (const uint4*)xh;   // [N][2] uint4
    float di = dinv[node];
    int start = offs[node], end = offs[node + 1];
    float acc[8] = {0.f, 0.f, 0.f, 0.f, 0.f, 0.f, 0.f, 0.f};
    if (way == 0) {
        uint4 r = x2[(size_t)node * 2 + comp];
        const __half2* hp = (const __half2*)&r;
        #pragma unroll
        for (int c = 0; c < 4; ++c) {
            float2 f = __half22float2(hp[c]);
            acc[c * 2]     = di * f.x;
            acc[c * 2 + 1] = di * f.y;
        }
    }
    int j = start + way;
    for (; j + 8 < end; j += 16) {
        int s0 = csr[j], s1 = csr[j + 8];
        float w0 = dinv[s0], w1 = dinv[s1];
        uint4 r0 = x2[(size_t)s0 * 2 + comp];
        uint4 r1 = x2[(size_t)s1 * 2 + comp];
        const __half2* hp0 = (const __half2*)&r0;
        const __half2* hp1 = (const __half2*)&r1;
        #pragma unroll
        for (int c = 0; c < 4; ++c) {
            float2 f0 = __half22float2(hp0[c]);
            float2 f1 = __half22float2(hp1[c]);
            acc[c * 2]     += w0 * f0.x + w1 * f1.x;
            acc[c * 2 + 1] += w0 * f0.y + w1 * f1.y;
        }
    }
    if (j < end) {
        int s = csr[j];
        float w = dinv[s];
        uint4 r = x2[(size_t)s * 2 + comp];
        const __half2* hp = (const __half2*)&r;
        #pragma unroll
        for (int c = 0; c < 4; ++c) {
            float2 f = __half22float2(hp[c]);
            acc[c * 2]     += w * f.x;
            acc[c * 2 + 1] += w * f.y;
        }
    }
    #pragma unroll
    for (int m = 1; m <= 4; m <<= 1) {
        #pragma unroll
        for (int c = 0; c < 8; ++c) acc[c] += __shfl_xor(acc[c], m, 64);
    }
    if (way == 0) {
        float4* ax = (float4*)aggX;
        ax[(size_t)node * 4 + comp * 2 + 0] =
            make_float4(di * acc[0], di * acc[1], di * acc[2], di * acc[3]);
        ax[(size_t)node * 4 + comp * 2 + 1] =
            make_float4(di * acc[4], di * acc[5], di * acc[6], di * acc[7]);
    }
}

// ---------------------------------------------------------------------------
// Dense part: h2 = relu(aggX @ W1 + b1) @ W2, 64-node tile per block,
// thread = (node, quarter). h2 stored FP16 (3.2 MB -> L2-resident).
// ---------------------------------------------------------------------------
#define AGG_P 20   // 16 + 4 pad: keeps every 4-float chunk 16B-aligned
#define H1_P  68   // 64 + 4 pad
__global__ __launch_bounds__(256) void k_gemm12(
    const float* __restrict__ aggX,
    const float* __restrict__ W1, const float* __restrict__ b1,
    const float* __restrict__ W2, __half* __restrict__ h2, int N)
{
    __shared__ float W1s[IN_DIM * HID_DIM];    // 4 KB
    __shared__ float W2s[HID_DIM * OUT_DIM];   // 8 KB
    __shared__ float b1s[HID_DIM];
    __shared__ float aggs[64 * AGG_P];         // 5 KB
    __shared__ float h1s[64 * H1_P];           // 17 KB

    int tid = threadIdx.x;
    int base = blockIdx.x * 64;
    for (int i = tid; i < IN_DIM * HID_DIM; i += 256) W1s[i] = W1[i];
    for (int i = tid; i < HID_DIM * OUT_DIM; i += 256) W2s[i] = W2[i];
    if (tid < HID_DIM) b1s[tid] = b1[tid];

    {
        int node = tid >> 2, comp = tid & 3;
        float4 v = (base + node < N) ? ((const float4*)aggX)[(size_t)(base + node) * 4 + comp]
                                     : make_float4(0.f, 0.f, 0.f, 0.f);
        *(float4*)&aggs[node * AGG_P + comp * 4] = v;
    }
    __syncthreads();

    int node = tid >> 2, q = tid & 3;

    // GEMM1 + ReLU: cols q*16 .. q*16+15
    {
        float acc[16];
        #pragma unroll
        for (int c = 0; c < 16; ++c) acc[c] = b1s[q * 16 + c];
        #pragma unroll
        for (int k = 0; k < IN_DIM; ++k) {
            float a = aggs[node * AGG_P + k];
            const float4* wr = (const float4*)&W1s[k * HID_DIM + q * 16];
            #pragma unroll
            for (int c4 = 0; c4 < 4; ++c4) {
                float4 w = wr[c4];
                acc[c4 * 4 + 0] += a * w.x; acc[c4 * 4 + 1] += a * w.y;
                acc[c4 * 4 + 2] += a * w.z; acc[c4 * 4 + 3] += a * w.w;
            }
        }
        float4* h1row = (float4*)&h1s[node * H1_P + q * 16];
        #pragma unroll
        for (int c4 = 0; c4 < 4; ++c4)
            h1row[c4] = make_float4(fmaxf(acc[c4 * 4 + 0], 0.f), fmaxf(acc[c4 * 4 + 1], 0.f),
                                    fmaxf(acc[c4 * 4 + 2], 0.f), fmaxf(acc[c4 * 4 + 3], 0.f));
    }
    __syncthreads();

    // GEMM2: cols q*8 .. q*8+7 -> fp16 store (one uint4 = 8 halves)
    {
        float acc2[8];
        #pragma unroll
        for (int c = 0; c < 8; ++c) acc2[c] = 0.f;
        const float4* h1row = (const float4*)&h1s[node * H1_P];
        #pragma unroll
        for (int k4 = 0; k4 < 16; ++k4) {
            float4 hv = h1row[k4];
            float hvv[4] = {hv.x, hv.y, hv.z, hv.w};
            #pragma unroll
            for (int kk = 0; kk < 4; ++kk) {
                int k = k4 * 4 + kk;
                const float4* wr = (const float4*)&W2s[k * OUT_DIM + q * 8];
                float4 w0 = wr[0], w1 = wr[1];
                acc2[0] += hvv[kk] * w0.x; acc2[1] += hvv[kk] * w0.y;
                acc2[2] += hvv[kk] * w0.z; acc2[3] += hvv[kk] * w0.w;
                acc2[4] += hvv[kk] * w1.x; acc2[5] += hvv[kk] * w1.y;
                acc2[6] += hvv[kk] * w1.z; acc2[7] += hvv[kk] * w1.w;
            }
        }
        if (base + node < N) {
            __half2 p[4];
            #pragma unroll
            for (int c = 0; c < 4; ++c)
                p[c] = __floats2half2_rn(acc2[c * 2], acc2[c * 2 + 1]);
            ((uint4*)h2)[(size_t)(base + node) * 4 + q] = *(uint4*)p;
        }
    }
}

// ---------------------------------------------------------------------------
// Layer-2 gather: 4 nodes per wave; each node owns 16 lanes = 2 comps
// (2x uint4 = 16 fp16 ch = 32 B of the 64 B row) x 8 edge-ways -> avg-deg
// node = 1 serial chain iteration, 2 independent row-loads per edge.
// out[i][c] = b2[c] + di*(di*h2[i][c] + sum_s dinv_s*h2[s][c])
// ---------------------------------------------------------------------------
__global__ __launch_bounds__(256) void k_agg2(
    const __half* __restrict__ h2, const float* __restrict__ dinv,
    const int* __restrict__ offs, const unsigned short* __restrict__ csr,
    const float* __restrict__ b2, float* __restrict__ out, int N)
{
    int gtid = blockIdx.x * 256 + threadIdx.x;
    int lane = gtid & 63;
    int g = lane >> 4, sub = lane & 15;
    int comp = sub >> 3;     // 0..1 : which 32 B half of the 64 B row
    int way  = sub & 7;      // 0..7 edge ways
    int node = (gtid >> 6) * 4 + g;
    if (node >= N) return;
    const uint4* h24 = (const uint4*)h2;   // [N][4] uint4
    float di = dinv[node];
    int start = offs[node], end = offs[node + 1];
    float acc[16];
    #pragma unroll
    for (int c = 0; c < 16; ++c) acc[c] = 0.f;
    if (way == 0) {
        uint4 r0 = h24[(size_t)node * 4 + comp * 2 + 0];
        uint4 r1 = h24[(size_t)node * 4 + comp * 2 + 1];
        const __half2* hp0 = (const __half2*)&r0;
        const __half2* hp1 = (const __half2*)&r1;
        #pragma unroll
        for (int c = 0; c < 4; ++c) {
            float2 f0 = __half22float2(hp0[c]);
            float2 f1 = __half22float2(hp1[c]);
            acc[c * 2]         = di * f0.x;
            acc[c * 2 + 1]     = di * f0.y;
            acc[8 + c * 2]     = di * f1.x;
            acc[8 + c * 2 + 1] = di * f1.y;
        }
    }
    int j = start + way;
    for (; j + 8 < end; j += 16) {
        int s0 = csr[j], s1 = csr[j + 8];
        float w0 = dinv[s0], w1 = dinv[s1];
        uint4 a0 = h24[(size_t)s0 * 4 + comp * 2 + 0];
        uint4 a1 = h24[(size_t)s0 * 4 + comp * 2 + 1];
        uint4 b0 = h24[(size_t)s1 * 4 + comp * 2 + 0];
        uint4 b1 = h24[(size_t)s1 * 4 + comp * 2 + 1];
        const __half2* pa0 = (const __half2*)&a0;
        const __half2* pa1 = (const __half2*)&a1;
        const __half2* pb0 = (const __half2*)&b0;
        const __half2* pb1 = (const __half2*)&b1;
        #pragma unroll
        for (int c = 0; c < 4; ++c) {
            float2 fa0 = __half22float2(pa0[c]);
            float2 fa1 = __half22float2(pa1[c]);
            float2 fb0 = __half22float2(pb0[c]);
            float2 fb1 = __half22float2(pb1[c]);
            acc[c * 2]         += w0 * fa0.x + w1 * fb0.x;
            acc[c * 2 + 1]     += w0 * fa0.y + w1 * fb0.y;
            acc[8 + c * 2]     += w0 * fa1.x + w1 * fb1.x;
            acc[8 + c * 2 + 1] += w0 * fa1.y + w1 * fb1.y;
        }
    }
    if (j < end) {
        int s = csr[j];
        float w = dinv[s];
        uint4 a0 = h24[(size_t)s * 4 + comp * 2 + 0];
        uint4 a1 = h24[(size_t)s * 4 + comp * 2 + 1];
        const __half2* pa0 = (const __half2*)&a0;
        const __half2* pa1 = (const __half2*)&a1;
        #pragma unroll
        for (int c = 0; c < 4; ++c) {
            float2 f0 = __half22float2(pa0[c]);
            float2 f1 = __half22float2(pa1[c]);
            acc[c * 2]         += w * f0.x;
            acc[c * 2 + 1]     += w * f0.y;
            acc[8 + c * 2]     += w * f1.x;
            acc[8 + c * 2 + 1] += w * f1.y;
        }
    }
    #pragma unroll
    for (int m = 1; m <= 4; m <<= 1) {
        #pragma unroll
        for (int c = 0; c < 16; ++c) acc[c] += __shfl_xor(acc[c], m, 64);
    }
    if (way == 0) {
        const float4* b24 = (const float4*)b2;
        float4* out4 = (float4*)out;
        #pragma unroll
        for (int h = 0; h < 2; ++h) {
            float4 bb = b24[comp * 4 + h * 2 + 0];
            float4 bc = b24[comp * 4 + h * 2 + 1];
            // wait: out row is 128 B = 8 float4; comp covers 4 of them
            out4[(size_t)node * 8 + comp * 4 + h * 2 + 0] =
                make_float4(di * acc[h * 8 + 0] + bb.x, di * acc[h * 8 + 1] + bb.y,
                            di * acc[h * 8 + 2] + bb.z, di * acc[h * 8 + 3] + bb.w);
            out4[(size_t)node * 8 + comp * 4 + h * 2 + 1] =
                make_float4(di * acc[h * 8 + 4] + bc.x, di * acc[h * 8 + 5] + bc.y,
                            di * acc[h * 8 + 6] + bc.z, di * acc[h * 8 + 7] + bc.w);
        }
    }
}

extern "C" void kernel_launch(void* const* d_in, const int* in_sizes, int n_in,
                              void* d_out, int out_size, void* d_ws, size_t ws_size,
                              hipStream_t stream) {
    const float* x     = (const float*)d_in[0];
    const void*  edges = d_in[1];
    const float* W1    = (const float*)d_in[2];
    const float* b1    = (const float*)d_in[3];
    const float* W2    = (const float*)d_in[4];
    const float* b2    = (const float*)d_in[5];
    float* out = (float*)d_out;

    const int       N = in_sizes[0] / IN_DIM;   // 50000 (fits u16)
    const long long E = in_sizes[1] / 2;        // 800000
    const int    NBUK = (N + 255) >> 8;         // 196 coarse buckets (<=256)
    const int   NBLKA = (int)((E + EPB - 1) / EPB);

    // ws layout: csr [E u16, pad to 16B] | gpart [NBUK*CAP u32] | xh [16N half]
    //            | aggX [16N f] | h2 [32N half] | dinv [N f] | offs [N+1] | gcur [NBUK]
    unsigned short* csr   = (unsigned short*)d_ws;
    unsigned int*   gpart = (unsigned int*)(csr + ((E + 7) & ~7LL));
    __half* xh       = (__half*)(gpart + (size_t)NBUK * CAP);
    float*  aggX     = (float*)(xh + (size_t)IN_DIM * N);
    __half* h2       = (__half*)(aggX + (size_t)IN_DIM * N);
    float*  dinv     = (float*)(h2 + (size_t)OUT_DIM * N);
    int*    offs     = (int*)(dinv + N);
    int*    gcur     = offs + N + 1;

    const int B = 256;
    hipMemsetAsync(gcur, 0, (size_t)NBUK * sizeof(int), stream);
    k_partA<<<NBLKA + CONVB, B, 0, stream>>>(edges, gcur, gpart, NBUK, E,
                                             x, xh, (long long)N * IN_DIM, NBLKA);
    k_partB<<<NBUK, B, 0, stream>>>(gcur, gpart, csr, offs, dinv, NBUK, N);

    // 4 nodes per wave -> 16 nodes per 256-thread block
    k_agg1<<<(N + 15) / 16, B, 0, stream>>>(xh, dinv, offs, csr, aggX, N);
    k_gemm12<<<(N + 63) / 64, B, 0, stream>>>(aggX, W1, b1, W2, h2, N);
    k_agg2<<<(N + 15) / 16, B, 0, stream>>>(h2, dinv, offs, csr, b2, out, N);
}

// Round 17
// 135.831 us; speedup vs baseline: 1.0560x; 1.0560x over previous
//
#include <hip/hip_runtime.h>
#include <hip/hip_fp16.h>

#define IN_DIM  16
#define HID_DIM 64
#define OUT_DIM 32

#define CAP   8192  // per-bucket capacity in gpart (mean 4096, +64 sigma)
#define EPB   3328  // edges per partA block = 256 threads x 13 regs
#define CONVB 64    // extra partA blocks that convert x -> fp16

// ---------------------------------------------------------------------------
// Edge dtype: reference says int64, harness doc says int32. Detect inline:
// nonneg int64 < 2^31 has every odd 32-bit word == 0.
// ---------------------------------------------------------------------------
__device__ __forceinline__ int detect_is64(const void* edges) {
    const int* w = (const int*)edges;
    int is64 = 1;
    #pragma unroll
    for (int i = 0; i < 16; ++i) is64 &= (w[2 * i + 1] == 0);
    return is64;
}

__device__ __forceinline__ long long edge_at(const void* edges, int is64, long long i) {
    if (is64) return ((const long long*)edges)[i];
    return (long long)((const int*)edges)[i];
}

// ---------------------------------------------------------------------------
// partA: coarse partition by dst>>8 into per-bucket private regions of gpart
// (serial per-thread flush: 64 stores/wave-instr, all buckets in parallel —
// measured better than wave-cooperative flush, r13/14/16 vs r12/15).
// Blocks >= nblkA convert x -> fp16 (ride-along). Entry: src|((dst&255)<<16).
// ---------------------------------------------------------------------------
__global__ __launch_bounds__(256) void k_partA(const void* edges, int* gcur,
                                               unsigned int* gpart, int nbuk, long long E,
                                               const float* __restrict__ x,
                                               __half* __restrict__ xh,
                                               long long xElems, int nblkA) {
    if (blockIdx.x >= nblkA) {
        // x -> fp16 conversion, grid-stride, coalesced
        const float4* x4 = (const float4*)x;
        uint2* outp = (uint2*)xh;
        long long n4 = xElems >> 2;
        for (long long i = (long long)(blockIdx.x - nblkA) * 256 + threadIdx.x;
             i < n4; i += (long long)CONVB * 256) {
            float4 v = x4[i];
            __half2 a = __floats2half2_rn(v.x, v.y);
            __half2 b = __floats2half2_rn(v.z, v.w);
            outp[i] = make_uint2(*(unsigned int*)&a, *(unsigned int*)&b);
        }
        return;
    }

    __shared__ unsigned int staged[EPB];     // 13 KB
    __shared__ int hcnt[256], hoff[256], hcur[256];
    __shared__ int s64s;
    int t = threadIdx.x;
    if (t == 0) s64s = detect_is64(edges);
    hcnt[t] = 0;
    __syncthreads();
    int is64 = s64s;

    long long e0 = (long long)blockIdx.x * EPB;
    unsigned int rs[13], rd[13];
    int nval = 0;
    #pragma unroll
    for (int k = 0; k < 13; ++k) {
        long long e = e0 + t + k * 256;
        if (e < E) {
            rs[k] = (unsigned int)edge_at(edges, is64, e);
            rd[k] = (unsigned int)edge_at(edges, is64, E + e);
            atomicAdd(&hcnt[rd[k] >> 8], 1);
            nval = k + 1;
        }
    }
    __syncthreads();

    // inclusive scan of hcnt -> exclusive offsets
    int v = hcnt[t];
    hoff[t] = v;
    __syncthreads();
    for (int d = 1; d < 256; d <<= 1) {
        int u = (t >= d) ? hoff[t - d] : 0;
        __syncthreads();
        hoff[t] += u;
        __syncthreads();
    }
    int excl = hoff[t] - v;
    hoff[t] = excl;
    hcur[t] = excl;
    __syncthreads();

    #pragma unroll
    for (int k = 0; k < 13; ++k) {
        if (k < nval) {
            int p = atomicAdd(&hcur[rd[k] >> 8], 1);
            staged[p] = rs[k] | ((rd[k] & 255u) << 16);
        }
    }
    __syncthreads();

    if (t < nbuk) {
        int c = hcnt[t];
        if (c > 0) {
            int base = atomicAdd(&gcur[t], c);
            int o = hoff[t];
            for (int k = 0; k < c; ++k) {
                int idx = base + k;
                if (idx < CAP) gpart[(size_t)t * CAP + idx] = staged[o + k];
            }
        }
    }
}

// ---------------------------------------------------------------------------
// partB: one block per bucket. Contiguous coalesced read of the bucket's CAP
// region; fine-sort by dst&255; writes dinv/offs and u16 src csr.
// Requires nbuk <= 256 and N <= 65536.
// ---------------------------------------------------------------------------
__global__ __launch_bounds__(256) void k_partB(const int* __restrict__ gcur,
                                               const unsigned int* __restrict__ gpart,
                                               unsigned short* __restrict__ csr,
                                               int* __restrict__ offs,
                                               float* __restrict__ dinv,
                                               int nbuk, int N) {
    __shared__ unsigned int ebuf[CAP];       // 32 KB
    __shared__ int bscan[256];
    __shared__ int hcnt[256], hoff[256], hcur[256];
    int t = threadIdx.x;
    int b = blockIdx.x;

    // redundant scan of bucket counts -> this bucket's global base
    int bc = (t < nbuk) ? min(gcur[t], CAP) : 0;
    bscan[t] = bc;
    hcnt[t] = 0;
    __syncthreads();
    for (int d = 1; d < 256; d <<= 1) {
        int u = (t >= d) ? bscan[t - d] : 0;
        __syncthreads();
        bscan[t] += u;
        __syncthreads();
    }
    int base = (b == 0) ? 0 : bscan[b - 1];
    int cnt  = bscan[b] - base;

    for (int i = t; i < cnt; i += 256) ebuf[i] = gpart[(size_t)b * CAP + i];
    __syncthreads();
    for (int i = t; i < cnt; i += 256) atomicAdd(&hcnt[(ebuf[i] >> 16) & 255u], 1);
    __syncthreads();

    int v = hcnt[t];
    hoff[t] = v;
    __syncthreads();
    for (int d = 1; d < 256; d <<= 1) {
        int u = (t >= d) ? hoff[t - d] : 0;
        __syncthreads();
        hoff[t] += u;
        __syncthreads();
    }
    int excl = hoff[t] - v;
    hcur[t] = excl;
    __syncthreads();

    int node = b * 256 + t;
    if (node < N) {
        offs[node] = base + excl;
        dinv[node] = rsqrtf((float)v + 1.0f);
    }
    if (b == nbuk - 1 && t == 0) offs[N] = bscan[nbuk - 1];

    // scatter u16 src into this bucket's private csr window
    for (int i = t; i < cnt; i += 256) {
        unsigned int e = ebuf[i];
        int dl = (e >> 16) & 255;
        int p = atomicAdd(&hcur[dl], 1);
        csr[base + p] = (unsigned short)(e & 0xffffu);
    }
}

// ---------------------------------------------------------------------------
// Layer-1 gather (fp16 x): 4 nodes per wave; each node owns 16 lanes =
// 2 comps (uint4 = 8 fp16 ch of the 32 B row) x 8 edge-ways. Avg-deg node =
// 1 unrolled iteration. Reduction = 3 xor steps over the way bits.
// aggX[i][:] = di*(di*x_i + sum_s dinv_s*x_s)   (fp32 out)
// ---------------------------------------------------------------------------
__global__ __launch_bounds__(256) void k_agg1(
    const __half* __restrict__ xh, const float* __restrict__ dinv,
    const int* __restrict__ offs, const unsigned short* __restrict__ csr,
    float* __restrict__ aggX, int N)
{
    int gtid = blockIdx.x * 256 + threadIdx.x;
    int lane = gtid & 63;
    int g = lane >> 4, sub = lane & 15;
    int comp = sub >> 3;     // 0..1 : which 8-channel (16 B) half of the row
    int way  = sub & 7;      // 0..7 edge ways
    int node = (gtid >> 6) * 4 + g;
    if (node >= N) return;
    const uint4* x2 = (const uint4*)xh;   // [N][2] uint4
    float di = dinv[node];
    int start = offs[node], end = offs[node + 1];
    float acc[8] = {0.f, 0.f, 0.f, 0.f, 0.f, 0.f, 0.f, 0.f};
    if (way == 0) {
        uint4 r = x2[(size_t)node * 2 + comp];
        const __half2* hp = (const __half2*)&r;
        #pragma unroll
        for (int c = 0; c < 4; ++c) {
            float2 f = __half22float2(hp[c]);
            acc[c * 2]     = di * f.x;
            acc[c * 2 + 1] = di * f.y;
        }
    }
    int j = start + way;
    for (; j + 8 < end; j += 16) {
        int s0 = csr[j], s1 = csr[j + 8];
        float w0 = dinv[s0], w1 = dinv[s1];
        uint4 r0 = x2[(size_t)s0 * 2 + comp];
        uint4 r1 = x2[(size_t)s1 * 2 + comp];
        const __half2* hp0 = (const __half2*)&r0;
        const __half2* hp1 = (const __half2*)&r1;
        #pragma unroll
        for (int c = 0; c < 4; ++c) {
            float2 f0 = __half22float2(hp0[c]);
            float2 f1 = __half22float2(hp1[c]);
            acc[c * 2]     += w0 * f0.x + w1 * f1.x;
            acc[c * 2 + 1] += w0 * f0.y + w1 * f1.y;
        }
    }
    if (j < end) {
        int s = csr[j];
        float w = dinv[s];
        uint4 r = x2[(size_t)s * 2 + comp];
        const __half2* hp = (const __half2*)&r;
        #pragma unroll
        for (int c = 0; c < 4; ++c) {
            float2 f = __half22float2(hp[c]);
            acc[c * 2]     += w * f.x;
            acc[c * 2 + 1] += w * f.y;
        }
    }
    #pragma unroll
    for (int m = 1; m <= 4; m <<= 1) {
        #pragma unroll
        for (int c = 0; c < 8; ++c) acc[c] += __shfl_xor(acc[c], m, 64);
    }
    if (way == 0) {
        float4* ax = (float4*)aggX;
        ax[(size_t)node * 4 + comp * 2 + 0] =
            make_float4(di * acc[0], di * acc[1], di * acc[2], di * acc[3]);
        ax[(size_t)node * 4 + comp * 2 + 1] =
            make_float4(di * acc[4], di * acc[5], di * acc[6], di * acc[7]);
    }
}

// ---------------------------------------------------------------------------
// Dense part: h2 = relu(aggX @ W1 + b1) @ W2, 64-node tile per block,
// thread = (node, quarter). h2 stored FP16 (3.2 MB -> L2-resident).
// ---------------------------------------------------------------------------
#define AGG_P 20   // 16 + 4 pad: keeps every 4-float chunk 16B-aligned
#define H1_P  68   // 64 + 4 pad
__global__ __launch_bounds__(256) void k_gemm12(
    const float* __restrict__ aggX,
    const float* __restrict__ W1, const float* __restrict__ b1,
    const float* __restrict__ W2, __half* __restrict__ h2, int N)
{
    __shared__ float W1s[IN_DIM * HID_DIM];    // 4 KB
    __shared__ float W2s[HID_DIM * OUT_DIM];   // 8 KB
    __shared__ float b1s[HID_DIM];
    __shared__ float aggs[64 * AGG_P];         // 5 KB
    __shared__ float h1s[64 * H1_P];           // 17 KB

    int tid = threadIdx.x;
    int base = blockIdx.x * 64;
    for (int i = tid; i < IN_DIM * HID_DIM; i += 256) W1s[i] = W1[i];
    for (int i = tid; i < HID_DIM * OUT_DIM; i += 256) W2s[i] = W2[i];
    if (tid < HID_DIM) b1s[tid] = b1[tid];

    {
        int node = tid >> 2, comp = tid & 3;
        float4 v = (base + node < N) ? ((const float4*)aggX)[(size_t)(base + node) * 4 + comp]
                                     : make_float4(0.f, 0.f, 0.f, 0.f);
        *(float4*)&aggs[node * AGG_P + comp * 4] = v;
    }
    __syncthreads();

    int node = tid >> 2, q = tid & 3;

    // GEMM1 + ReLU: cols q*16 .. q*16+15
    {
        float acc[16];
        #pragma unroll
        for (int c = 0; c < 16; ++c) acc[c] = b1s[q * 16 + c];
        #pragma unroll
        for (int k = 0; k < IN_DIM; ++k) {
            float a = aggs[node * AGG_P + k];
            const float4* wr = (const float4*)&W1s[k * HID_DIM + q * 16];
            #pragma unroll
            for (int c4 = 0; c4 < 4; ++c4) {
                float4 w = wr[c4];
                acc[c4 * 4 + 0] += a * w.x; acc[c4 * 4 + 1] += a * w.y;
                acc[c4 * 4 + 2] += a * w.z; acc[c4 * 4 + 3] += a * w.w;
            }
        }
        float4* h1row = (float4*)&h1s[node * H1_P + q * 16];
        #pragma unroll
        for (int c4 = 0; c4 < 4; ++c4)
            h1row[c4] = make_float4(fmaxf(acc[c4 * 4 + 0], 0.f), fmaxf(acc[c4 * 4 + 1], 0.f),
                                    fmaxf(acc[c4 * 4 + 2], 0.f), fmaxf(acc[c4 * 4 + 3], 0.f));
    }
    __syncthreads();

    // GEMM2: cols q*8 .. q*8+7 -> fp16 store (one uint4 = 8 halves)
    {
        float acc2[8];
        #pragma unroll
        for (int c = 0; c < 8; ++c) acc2[c] = 0.f;
        const float4* h1row = (const float4*)&h1s[node * H1_P];
        #pragma unroll
        for (int k4 = 0; k4 < 16; ++k4) {
            float4 hv = h1row[k4];
            float hvv[4] = {hv.x, hv.y, hv.z, hv.w};
            #pragma unroll
            for (int kk = 0; kk < 4; ++kk) {
                int k = k4 * 4 + kk;
                const float4* wr = (const float4*)&W2s[k * OUT_DIM + q * 8];
                float4 w0 = wr[0], w1 = wr[1];
                acc2[0] += hvv[kk] * w0.x; acc2[1] += hvv[kk] * w0.y;
                acc2[2] += hvv[kk] * w0.z; acc2[3] += hvv[kk] * w0.w;
                acc2[4] += hvv[kk] * w1.x; acc2[5] += hvv[kk] * w1.y;
                acc2[6] += hvv[kk] * w1.z; acc2[7] += hvv[kk] * w1.w;
            }
        }
        if (base + node < N) {
            __half2 p[4];
            #pragma unroll
            for (int c = 0; c < 4; ++c)
                p[c] = __floats2half2_rn(acc2[c * 2], acc2[c * 2 + 1]);
            ((uint4*)h2)[(size_t)(base + node) * 4 + q] = *(uint4*)p;
        }
    }
}

// ---------------------------------------------------------------------------
// Layer-2 gather: 4 nodes per wave; each node owns 16 lanes = 4 comps
// (uint4 = 8 fp16 ch of the 64 B row) x 4 edge-ways. Reduction = 2 xor steps.
// out[i][c] = b2[c] + di*(di*h2[i][c] + sum_s dinv_s*h2[s][c])
// ---------------------------------------------------------------------------
__global__ __launch_bounds__(256) void k_agg2(
    const __half* __restrict__ h2, const float* __restrict__ dinv,
    const int* __restrict__ offs, const unsigned short* __restrict__ csr,
    const float* __restrict__ b2, float* __restrict__ out, int N)
{
    int gtid = blockIdx.x * 256 + threadIdx.x;
    int lane = gtid & 63;
    int g = lane >> 4, sub = lane & 15;
    int comp = sub & 3, way = sub >> 2;           // 4 comps x 4 ways
    int node = (gtid >> 6) * 4 + g;
    if (node >= N) return;
    const uint4* h24 = (const uint4*)h2;
    float di = dinv[node];
    int start = offs[node], end = offs[node + 1];
    float acc[8] = {0.f, 0.f, 0.f, 0.f, 0.f, 0.f, 0.f, 0.f};
    if (way == 0) {
        uint4 r = h24[(size_t)node * 4 + comp];
        const __half2* hp = (const __half2*)&r;
        #pragma unroll
        for (int c = 0; c < 4; ++c) {
            float2 f = __half22float2(hp[c]);
            acc[c * 2]     = di * f.x;
            acc[c * 2 + 1] = di * f.y;
        }
    }
    int j = start + way;
    for (; j + 4 < end; j += 8) {
        int s0 = csr[j], s1 = csr[j + 4];
        float w0 = dinv[s0], w1 = dinv[s1];
        uint4 r0 = h24[(size_t)s0 * 4 + comp];
        uint4 r1 = h24[(size_t)s1 * 4 + comp];
        const __half2* hp0 = (const __half2*)&r0;
        const __half2* hp1 = (const __half2*)&r1;
        #pragma unroll
        for (int c = 0; c < 4; ++c) {
            float2 f0 = __half22float2(hp0[c]);
            float2 f1 = __half22float2(hp1[c]);
            acc[c * 2]     += w0 * f0.x + w1 * f1.x;
            acc[c * 2 + 1] += w0 * f0.y + w1 * f1.y;
        }
    }
    if (j < end) {
        int s = csr[j];
        float w = dinv[s];
        uint4 r = h24[(size_t)s * 4 + comp];
        const __half2* hp = (const __half2*)&r;
        #pragma unroll
        for (int c = 0; c < 4; ++c) {
            float2 f = __half22float2(hp[c]);
            acc[c * 2]     += w * f.x;
            acc[c * 2 + 1] += w * f.y;
        }
    }
    #pragma unroll
    for (int m = 4; m <= 8; m <<= 1) {
        #pragma unroll
        for (int c = 0; c < 8; ++c) acc[c] += __shfl_xor(acc[c], m, 64);
    }
    if (way == 0) {
        const float4* b24 = (const float4*)b2;
        float4 bb0 = b24[comp * 2], bb1 = b24[comp * 2 + 1];
        float4* out4 = (float4*)out;
        out4[(size_t)node * 8 + comp * 2 + 0] =
            make_float4(di * acc[0] + bb0.x, di * acc[1] + bb0.y,
                        di * acc[2] + bb0.z, di * acc[3] + bb0.w);
        out4[(size_t)node * 8 + comp * 2 + 1] =
            make_float4(di * acc[4] + bb1.x, di * acc[5] + bb1.y,
                        di * acc[6] + bb1.z, di * acc[7] + bb1.w);
    }
}

extern "C" void kernel_launch(void* const* d_in, const int* in_sizes, int n_in,
                              void* d_out, int out_size, void* d_ws, size_t ws_size,
                              hipStream_t stream) {
    const float* x     = (const float*)d_in[0];
    const void*  edges = d_in[1];
    const float* W1    = (const float*)d_in[2];
    const float* b1    = (const float*)d_in[3];
    const float* W2    = (const float*)d_in[4];
    const float* b2    = (const float*)d_in[5];
    float* out = (float*)d_out;

    const int       N = in_sizes[0] / IN_DIM;   // 50000 (fits u16)
    const long long E = in_sizes[1] / 2;        // 800000
    const int    NBUK = (N + 255) >> 8;         // 196 coarse buckets (<=256)
    const int   NBLKA = (int)((E + EPB - 1) / EPB);

    // ws layout: csr [E u16, pad to 16B] | gpart [NBUK*CAP u32] | xh [16N half]
    //            | aggX [16N f] | h2 [32N half] | dinv [N f] | offs [N+1] | gcur [NBUK]
    unsigned short* csr   = (unsigned short*)d_ws;
    unsigned int*   gpart = (unsigned int*)(csr + ((E + 7) & ~7LL));
    __half* xh       = (__half*)(gpart + (size_t)NBUK * CAP);
    float*  aggX     = (float*)(xh + (size_t)IN_DIM * N);
    __half* h2       = (__half*)(aggX + (size_t)IN_DIM * N);
    float*  dinv     = (float*)(h2 + (size_t)OUT_DIM * N);
    int*    offs     = (int*)(dinv + N);
    int*    gcur     = offs + N + 1;

    const int B = 256;
    hipMemsetAsync(gcur, 0, (size_t)NBUK * sizeof(int), stream);
    k_partA<<<NBLKA + CONVB, B, 0, stream>>>(edges, gcur, gpart, NBUK, E,
                                             x, xh, (long long)N * IN_DIM, NBLKA);
    k_partB<<<NBUK, B, 0, stream>>>(gcur, gpart, csr, offs, dinv, NBUK, N);

    // 4 nodes per wave -> 16 nodes per 256-thread block
    k_agg1<<<(N + 15) / 16, B, 0, stream>>>(xh, dinv, offs, csr, aggX, N);
    k_gemm12<<<(N + 63) / 64, B, 0, stream>>>(aggX, W1, b1, W2, h2, N);
    k_agg2<<<(N + 15) / 16, B, 0, stream>>>(h2, dinv, offs, csr, b2, out, N);
}